// Round 11
// baseline (104.304 us; speedup 1.0000x reference)
//
#include <hip/hip_runtime.h>

#define N_BONDS 50000
#define N_EDGES 600000
#define R_BONDS 8
#define THREADS 256
#define BONDS_PER_BLOCK 32   // 4 waves * 8 bonds

typedef float f4 __attribute__((ext_vector_type(4)));

__device__ __forceinline__ float bcastf(float v, int l) {
    return __builtin_bit_cast(float, __builtin_amdgcn_readlane(__builtin_bit_cast(int, v), l));
}
__device__ __forceinline__ f4 f4zero() { return (f4){0.f, 0.f, 0.f, 0.f}; }
__device__ __forceinline__ void fma4(f4& a, float s, const f4& b) {
    a.x = fmaf(s, b.x, a.x); a.y = fmaf(s, b.y, a.y);
    a.z = fmaf(s, b.z, a.z); a.w = fmaf(s, b.w, a.w);
}

// ---- K0: starts[b] = lower_bound(seg, b) ----
__global__ __launch_bounds__(256)
void fill_starts(const int* __restrict__ edges, int* __restrict__ starts) {
    const int e = blockIdx.x * blockDim.x + threadIdx.x;
    if (e >= N_EDGES) return;
    const int2* edges2 = (const int2*)edges;
    const int s  = edges2[e].x;
    const int sp = (e == 0) ? -1 : edges2[e - 1].x;
    for (int b = sp + 1; b <= s; ++b) starts[b] = e;
    if (e == N_EDGES - 1)
        for (int b = s + 1; b <= N_BONDS; ++b) starts[b] = N_EDGES;
}

// ---- K1: bondK = bond @ Ktop (rows 0..63 of kernel) ----
__global__ __launch_bounds__(256, 4)
void premul_bond(const float* __restrict__ bond, const float* __restrict__ Kmat,
                 float* __restrict__ bondK) {
    __shared__ float ldsK[64 * 64];   // 16 KB: Ktop
    const int tid = threadIdx.x, lane = tid & 63, wid = tid >> 6;
    {
        const f4* K4 = (const f4*)Kmat;          // rows 0..63 = first 1024 f4
        f4* L4 = (f4*)ldsK;
        #pragma unroll
        for (int i = 0; i < 4; ++i) L4[tid + i * 256] = K4[tid + i * 256];
    }
    __syncthreads();
    const int row0 = blockIdx.x * BONDS_PER_BLOCK + wid * R_BONDS;
    if (row0 >= N_BONDS) return;

    float rowv[R_BONDS];
    #pragma unroll
    for (int r = 0; r < R_BONDS; ++r) {
        int ri = row0 + r; if (ri >= N_BONDS) ri = N_BONDS - 1;
        rowv[r] = __builtin_nontemporal_load(&bond[ri * 64 + lane]);
    }
    float acc[R_BONDS];
    #pragma unroll
    for (int r = 0; r < R_BONDS; ++r) acc[r] = 0.f;

    #pragma unroll 4
    for (int d = 0; d < 64; ++d) {
        const float k = ldsK[d * 64 + lane];     // lane = output unit
        #pragma unroll
        for (int r = 0; r < R_BONDS; ++r)
            acc[r] = fmaf(bcastf(rowv[r], d), k, acc[r]);
    }
    #pragma unroll
    for (int r = 0; r < R_BONDS; ++r)
        if (row0 + r < N_BONDS)
            __builtin_nontemporal_store(acc[r], &bondK[(row0 + r) * 64 + lane]);
}

// ---- K2: stream edges; out = segsum(gather(bondK)), Sbuf = segsum(sph) ----
__global__ __launch_bounds__(THREADS, 4)   // no LDS, no barrier, no matvec
void gather_segsum(const float* __restrict__ bondK, const float* __restrict__ sph,
                   const int* __restrict__ edges, const int* __restrict__ starts,
                   float* __restrict__ outG, float* __restrict__ Sbuf) {
    const int tid = threadIdx.x;
    const int lane = tid & 63;
    const int wid  = tid >> 6;
    const int fl   = lane & 15;
    const int sg   = lane >> 4;

    const int b0 = blockIdx.x * BONDS_PER_BLOCK + wid * R_BONDS;
    if (b0 >= N_BONDS) return;

    int st[R_BONDS + 1];                       // SGPR, static-indexed
    #pragma unroll
    for (int r = 0; r <= R_BONDS; ++r) {
        int ix = b0 + r; if (ix > N_BONDS) ix = N_BONDS;
        st[r] = __builtin_amdgcn_readfirstlane(starts[ix]);
    }
    const int eb = st[0], total = st[R_BONDS] - eb;

    const f4*   g4 = (const f4*)bondK;
    const f4*   s4 = (const f4*)sph;
    const int2* edges2 = (const int2*)edges;
    f4* oG = (f4*)outG;
    f4* oS = (f4*)Sbuf;
    const bool storer = (sg == 0);

    f4 aG = f4zero(), aS = f4zero();
    int r = 0, cs = 0, bnd = st[1] - eb;

    // cross-subgroup reduce: every lane ends with the 4-subgroup sum (f4 layout)
    auto xr = [&](f4 v) -> f4 {
        v.x += __shfl_xor(v.x, 16); v.y += __shfl_xor(v.y, 16);
        v.z += __shfl_xor(v.z, 16); v.w += __shfl_xor(v.w, 16);
        v.x += __shfl_xor(v.x, 32); v.y += __shfl_xor(v.y, 32);
        v.z += __shfl_xor(v.z, 32); v.w += __shfl_xor(v.w, 32);
        return v;
    };

    // boundary path: masked add; close bonds that end inside this quad (direct store)
    auto slowpath = [&](int q, f4 GV, f4 SV) {
        const int qe = q + sg;
        while (true) {
            const float m = (qe >= cs && qe < bnd) ? 1.f : 0.f;
            fma4(aG, m, GV); fma4(aS, m, SV);
            if (bnd > q + 4) break;            // bond continues past quad
            const f4 cg = xr(aG), csv = xr(aS);
            if (storer && b0 + r < N_BONDS) {
                __builtin_nontemporal_store(cg,  &oG[(b0 + r) * 16 + fl]);
                __builtin_nontemporal_store(csv, &oS[(b0 + r) * 16 + fl]);
            }
            aG = f4zero(); aS = f4zero();
            cs = bnd;
            ++r;
            if (r >= R_BONDS) { bnd = 0x7fffffff; break; }
            #pragma unroll
            for (int rr = 2; rr <= R_BONDS; ++rr)
                if (r + 1 == rr) bnd = st[rr] - eb;
        }
    };

    int w0 = 0;
    while (w0 < total) {
        int wlen = total - w0; if (wlen > 64) wlen = 64;
        int2 p = make_int2(0, 0);
        if (lane < wlen) p = edges2[eb + w0 + lane];   // coalesced index window
        const int ng = (wlen + 3) >> 2;

        f4 gA, sA, gB, sB, gC, sC, gD, sD;

#define ISS(QQ, GV, SV) do { \
        if ((QQ) < ng) { \
            const int idx_ = (QQ) * 4 + sg; \
            const int nbr_ = __shfl(p.y, idx_); \
            int qe_ = w0 + idx_; if (qe_ >= total) qe_ = total - 1; \
            GV = g4[nbr_ * 16 + fl]; \
            SV = __builtin_nontemporal_load(&s4[(eb + qe_) * 16 + fl]); \
        } else { GV = f4zero(); SV = f4zero(); } } while (0)

#define ACC(QQ, GV, SV) do { \
        const int q_ = w0 + (QQ) * 4; \
        if (q_ + 4 <= bnd) { aG += GV; aS += SV; } \
        else slowpath(q_, GV, SV); } while (0)

        ISS(0, gA, sA); ISS(1, gB, sB); ISS(2, gC, sC); ISS(3, gD, sD);
        int q = 0;
        for (; q + 4 <= ng; q += 4) {                  // rotated: 8 loads in flight
            ACC(q + 0, gA, sA); ISS(q + 4, gA, sA);
            ACC(q + 1, gB, sB); ISS(q + 5, gB, sB);
            ACC(q + 2, gC, sC); ISS(q + 6, gC, sC);
            ACC(q + 3, gD, sD); ISS(q + 7, gD, sD);
        }
        if (q + 0 < ng) ACC(q + 0, gA, sA);
        if (q + 1 < ng) ACC(q + 1, gB, sB);
        if (q + 2 < ng) ACC(q + 2, gC, sC);
#undef ISS
#undef ACC
        w0 += wlen;
    }

    // close the open bond + zero-fill remaining empties
    {
        const f4 cg = xr(aG), csv = xr(aS);
        if (r < R_BONDS && storer && b0 + r < N_BONDS) {
            __builtin_nontemporal_store(cg,  &oG[(b0 + r) * 16 + fl]);
            __builtin_nontemporal_store(csv, &oS[(b0 + r) * 16 + fl]);
        }
        const f4 z = f4zero();
        for (int bb = r + 1; bb < R_BONDS; ++bb) {
            if (storer && b0 + bb < N_BONDS) {
                __builtin_nontemporal_store(z, &oG[(b0 + bb) * 16 + fl]);
                __builtin_nontemporal_store(z, &oS[(b0 + bb) * 16 + fl]);
            }
        }
    }
}

// ---- K3: out = out + Sbuf @ Kbot (rows 64..127) + bias ----
__global__ __launch_bounds__(256, 4)
void finish_mm(const float* __restrict__ Sbuf, const float* __restrict__ Kmat,
               const float* __restrict__ bias, float* __restrict__ out) {
    __shared__ float ldsK[64 * 64];   // 16 KB: Kbot
    const int tid = threadIdx.x, lane = tid & 63, wid = tid >> 6;
    {
        const f4* K4 = (const f4*)Kmat;          // rows 64..127 start at f4 index 1024
        f4* L4 = (f4*)ldsK;
        #pragma unroll
        for (int i = 0; i < 4; ++i) L4[tid + i * 256] = K4[1024 + tid + i * 256];
    }
    __syncthreads();
    const int row0 = blockIdx.x * BONDS_PER_BLOCK + wid * R_BONDS;
    if (row0 >= N_BONDS) return;

    const float bl = bias[lane];
    float rowv[R_BONDS], acc[R_BONDS];
    #pragma unroll
    for (int r = 0; r < R_BONDS; ++r) {
        int ri = row0 + r; if (ri >= N_BONDS) ri = N_BONDS - 1;
        rowv[r] = __builtin_nontemporal_load(&Sbuf[ri * 64 + lane]);
        acc[r]  = out[ri * 64 + lane] + bl;      // gather contribution + bias
    }
    #pragma unroll 4
    for (int d = 0; d < 64; ++d) {
        const float k = ldsK[d * 64 + lane];
        #pragma unroll
        for (int r = 0; r < R_BONDS; ++r)
            acc[r] = fmaf(bcastf(rowv[r], d), k, acc[r]);
    }
    #pragma unroll
    for (int r = 0; r < R_BONDS; ++r)
        if (row0 + r < N_BONDS)
            __builtin_nontemporal_store(acc[r], &out[(row0 + r) * 64 + lane]);
}

// ---- fallback (R10-proven fused kernel) if ws too small ----
__global__ __launch_bounds__(THREADS, 4)
void fused_fallback(const float* __restrict__ bond, const float* __restrict__ sph,
                    const int* __restrict__ edges, const float* __restrict__ Kmat,
                    const float* __restrict__ bias, const int* __restrict__ starts,
                    float* __restrict__ out) {
    __shared__ float ldsK[128 * 64];
    const int tid = threadIdx.x, lane = tid & 63, wid = tid >> 6;
    const int fl = lane & 15, sg = lane >> 4;
    const float bl = bias[lane];
    const int b0 = blockIdx.x * BONDS_PER_BLOCK + wid * R_BONDS;
    int stv[R_BONDS + 1];
    #pragma unroll
    for (int r = 0; r <= R_BONDS; ++r) {
        int ix = b0 + r; if (ix > N_BONDS) ix = N_BONDS;
        stv[r] = starts[ix];
    }
    {
        const f4* K4 = (const f4*)Kmat; f4* L4 = (f4*)ldsK;
        #pragma unroll
        for (int i = 0; i < 8; ++i) L4[tid + i * THREADS] = K4[tid + i * THREADS];
    }
    __syncthreads();
    if (b0 >= N_BONDS) return;
    int st[R_BONDS + 1];
    #pragma unroll
    for (int r = 0; r <= R_BONDS; ++r) st[r] = __builtin_amdgcn_readfirstlane(stv[r]);
    const int eb = st[0], total = st[R_BONDS] - eb;
    const f4* bond4 = (const f4*)bond; const f4* sph4 = (const f4*)sph;
    const int2* edges2 = (const int2*)edges;
    float slotG[R_BONDS], slotS[R_BONDS];
    f4 aG = f4zero(), aS = f4zero();
    int r = 0, cs = 0, bnd = st[1] - eb;
    auto txr = [&](f4 v) -> float {
        v.x += __shfl_xor(v.x, 16); v.y += __shfl_xor(v.y, 16);
        v.z += __shfl_xor(v.z, 16); v.w += __shfl_xor(v.w, 16);
        v.x += __shfl_xor(v.x, 32); v.y += __shfl_xor(v.y, 32);
        v.z += __shfl_xor(v.z, 32); v.w += __shfl_xor(v.w, 32);
        const int src = lane >> 2;
        const float s0 = __shfl(v.x, src), s1 = __shfl(v.y, src);
        const float s2 = __shfl(v.z, src), s3 = __shfl(v.w, src);
        const float r01 = (lane & 1) ? s1 : s0;
        const float r23 = (lane & 1) ? s3 : s2;
        return (lane & 2) ? r23 : r01;
    };
    auto slowpath = [&](int q, f4 GV, f4 SV) {
        const int qe = q + sg;
        while (true) {
            const float m = (qe >= cs && qe < bnd) ? 1.f : 0.f;
            fma4(aG, m, GV); fma4(aS, m, SV);
            if (bnd > q + 4) break;
            const float tG = txr(aG), tS = txr(aS);
            #pragma unroll
            for (int rr = 0; rr < R_BONDS; ++rr)
                if (rr == r) { slotG[rr] = tG; slotS[rr] = tS; }
            aG = f4zero(); aS = f4zero();
            cs = bnd; ++r;
            if (r >= R_BONDS) { bnd = 0x7fffffff; break; }
            #pragma unroll
            for (int rr = 2; rr <= R_BONDS; ++rr)
                if (r + 1 == rr) bnd = st[rr] - eb;
        }
    };
    int w0 = 0;
    while (w0 < total) {
        int wlen = total - w0; if (wlen > 64) wlen = 64;
        int2 p = make_int2(0, 0);
        if (lane < wlen) p = edges2[eb + w0 + lane];
        const int ng = (wlen + 3) >> 2;
        f4 gA, sA, gB, sB, gC, sC, gD, sD;
#define ISS(QQ, GV, SV) do { \
        if ((QQ) < ng) { \
            const int idx_ = (QQ) * 4 + sg; \
            const int nbr_ = __shfl(p.y, idx_); \
            int qe_ = w0 + idx_; if (qe_ >= total) qe_ = total - 1; \
            GV = bond4[nbr_ * 16 + fl]; \
            SV = __builtin_nontemporal_load(&sph4[(eb + qe_) * 16 + fl]); \
        } else { GV = f4zero(); SV = f4zero(); } } while (0)
#define ACC(QQ, GV, SV) do { \
        const int q_ = w0 + (QQ) * 4; \
        if (q_ + 4 <= bnd) { aG += GV; aS += SV; } \
        else slowpath(q_, GV, SV); } while (0)
        ISS(0, gA, sA); ISS(1, gB, sB); ISS(2, gC, sC); ISS(3, gD, sD);
        int q = 0;
        for (; q + 4 <= ng; q += 4) {
            ACC(q + 0, gA, sA); ISS(q + 4, gA, sA);
            ACC(q + 1, gB, sB); ISS(q + 5, gB, sB);
            ACC(q + 2, gC, sC); ISS(q + 6, gC, sC);
            ACC(q + 3, gD, sD); ISS(q + 7, gD, sD);
        }
        if (q + 0 < ng) ACC(q + 0, gA, sA);
        if (q + 1 < ng) ACC(q + 1, gB, sB);
        if (q + 2 < ng) ACC(q + 2, gC, sC);
#undef ISS
#undef ACC
        w0 += wlen;
    }
    {
        const float tG = txr(aG), tS = txr(aS);
        #pragma unroll
        for (int rr = 0; rr < R_BONDS; ++rr) {
            if (rr == r)     { slotG[rr] = tG;  slotS[rr] = tS; }
            else if (rr > r) { slotG[rr] = 0.f; slotS[rr] = 0.f; }
        }
    }
    float acc[R_BONDS];
    #pragma unroll
    for (int rr = 0; rr < R_BONDS; ++rr) acc[rr] = bl;
    #pragma unroll 4
    for (int d = 0; d < 64; ++d) {
        const float kt = ldsK[d * 64 + lane];
        const float kb = ldsK[(64 + d) * 64 + lane];
        #pragma unroll
        for (int rr = 0; rr < R_BONDS; ++rr) {
            acc[rr] = fmaf(bcastf(slotG[rr], d), kt, acc[rr]);
            acc[rr] = fmaf(bcastf(slotS[rr], d), kb, acc[rr]);
        }
    }
    #pragma unroll
    for (int rr = 0; rr < R_BONDS; ++rr)
        if (b0 + rr < N_BONDS)
            __builtin_nontemporal_store(acc[rr], &out[(b0 + rr) * 64 + lane]);
}

extern "C" void kernel_launch(void* const* d_in, const int* in_sizes, int n_in,
                              void* d_out, int out_size, void* d_ws, size_t ws_size,
                              hipStream_t stream) {
    const float* bond  = (const float*)d_in[0];
    const float* sph   = (const float*)d_in[1];
    const int*   edges = (const int*)d_in[2];
    const float* Kmat  = (const float*)d_in[3];
    const float* bias  = (const float*)d_in[4];
    float* out = (float*)d_out;

    int*   starts = (int*)d_ws;                                  // 200 KB
    float* bondK  = (float*)((char*)d_ws + 262144);              // 12.8 MB
    float* Sbuf   = (float*)((char*)d_ws + 262144 + (size_t)N_BONDS * 64 * 4);

    const size_t need = 262144 + 2ull * N_BONDS * 64 * 4;
    const int nblocks = (N_BONDS + BONDS_PER_BLOCK - 1) / BONDS_PER_BLOCK;

    fill_starts<<<(N_EDGES + 255) / 256, 256, 0, stream>>>(edges, starts);

    if (ws_size >= need) {
        premul_bond<<<nblocks, 256, 0, stream>>>(bond, Kmat, bondK);
        gather_segsum<<<nblocks, THREADS, 0, stream>>>(bondK, sph, edges, starts,
                                                       out, Sbuf);
        finish_mm<<<nblocks, 256, 0, stream>>>(Sbuf, Kmat, bias, out);
    } else {
        fused_fallback<<<nblocks, THREADS, 0, stream>>>(bond, sph, edges, Kmat,
                                                        bias, starts, out);
    }
}

// Round 12
// 74.216 us; speedup vs baseline: 1.4054x; 1.4054x over previous
//
#include <hip/hip_runtime.h>

#define N_BONDS 50000
#define N_EDGES 600000
#define R_BONDS 4
#define THREADS 512
#define BONDS_PER_BLOCK 32   // 8 waves * 4 bonds

typedef float f4 __attribute__((ext_vector_type(4)));

__device__ __forceinline__ float bcastf(float v, int l) {
    return __builtin_bit_cast(float, __builtin_amdgcn_readlane(__builtin_bit_cast(int, v), l));
}
__device__ __forceinline__ f4 f4zero() { return (f4){0.f, 0.f, 0.f, 0.f}; }
__device__ __forceinline__ void fma4(f4& a, float s, const f4& b) {
    a.x = fmaf(s, b.x, a.x); a.y = fmaf(s, b.y, a.y);
    a.z = fmaf(s, b.z, a.z); a.w = fmaf(s, b.w, a.w);
}

// ---- kernel 1: starts[b] = lower_bound(seg, b), b in [0, N_BONDS] ----
__global__ __launch_bounds__(256)
void fill_starts(const int* __restrict__ edges, int* __restrict__ starts) {
    const int e = blockIdx.x * blockDim.x + threadIdx.x;
    if (e >= N_EDGES) return;
    const int2* edges2 = (const int2*)edges;
    const int s  = edges2[e].x;
    const int sp = (e == 0) ? -1 : edges2[e - 1].x;
    for (int b = sp + 1; b <= s; ++b) starts[b] = e;
    if (e == N_EDGES - 1)
        for (int b = s + 1; b <= N_BONDS; ++b) starts[b] = N_EDGES;
}

// ---- kernel 2: fused gather + segsum + matvec ----
__global__ __launch_bounds__(THREADS, 4)   // VGPR cap 128: room for the 8-load pipeline
void fused_gather_segsum_mm(const float* __restrict__ bond,   // [N_BONDS][64]
                            const float* __restrict__ sph,    // [N_EDGES][64]
                            const int*   __restrict__ edges,  // [N_EDGES][2]
                            const float* __restrict__ Kmat,   // [128][64]
                            const float* __restrict__ bias,   // [64]
                            const int*   __restrict__ starts, // [N_BONDS+1]
                            float* __restrict__ out)          // [N_BONDS][64]
{
    __shared__ float ldsK[128 * 64];   // 32 KB shared by 8 waves
    const int tid  = threadIdx.x;
    const int lane = tid & 63;
    const int wid  = tid >> 6;
    const int fl   = lane & 15;   // f4-column within a 64-float row
    const int sg   = lane >> 4;   // subgroup = edge-within-quad

    {   // stage K, coalesced 16B
        const f4* K4 = (const f4*)Kmat;
        f4*       L4 = (f4*)ldsK;
        #pragma unroll
        for (int i = 0; i < 4; ++i) L4[tid + i * THREADS] = K4[tid + i * THREADS];
    }
    __syncthreads();                                   // only barrier

    const int b0 = blockIdx.x * BONDS_PER_BLOCK + wid * R_BONDS;
    if (b0 >= N_BONDS) return;

    int st[R_BONDS + 1];                               // SGPR, static-indexed only
    #pragma unroll
    for (int r = 0; r <= R_BONDS; ++r)
        st[r] = __builtin_amdgcn_readfirstlane(starts[b0 + r]);

    const int eb    = st[0];
    const int total = st[R_BONDS] - eb;

    const f4*   bond4  = (const f4*)bond;
    const f4*   sph4   = (const f4*)sph;
    const int2* edges2 = (const int2*)edges;

    float slotG[R_BONDS], slotS[R_BONDS];              // static-indexed only
    f4 aG = f4zero(), aS = f4zero();
    int r = 0, cs = 0, bnd = st[1] - eb;

    // cross-subgroup reduce + transpose f4 layout -> scalar layout (lane d = feat d)
    auto txr = [&](f4 v) -> float {
        v.x += __shfl_xor(v.x, 16); v.y += __shfl_xor(v.y, 16);
        v.z += __shfl_xor(v.z, 16); v.w += __shfl_xor(v.w, 16);
        v.x += __shfl_xor(v.x, 32); v.y += __shfl_xor(v.y, 32);
        v.z += __shfl_xor(v.z, 32); v.w += __shfl_xor(v.w, 32);
        const int src = lane >> 2;
        const float s0 = __shfl(v.x, src), s1 = __shfl(v.y, src);
        const float s2 = __shfl(v.z, src), s3 = __shfl(v.w, src);
        const float r01 = (lane & 1) ? s1 : s0;
        const float r23 = (lane & 1) ? s3 : s2;
        return (lane & 2) ? r23 : r01;
    };

    // boundary path: masked add, close bonds that end inside this quad
    auto slowpath = [&](int q, f4 GV, f4 SV) {
        const int qe = q + sg;
        while (true) {
            const float m = (qe >= cs && qe < bnd) ? 1.f : 0.f;
            fma4(aG, m, GV); fma4(aS, m, SV);
            if (bnd > q + 4) break;                    // bond continues past quad
            const float tG = txr(aG), tS = txr(aS);    // close bond r
            #pragma unroll
            for (int rr = 0; rr < R_BONDS; ++rr)
                if (rr == r) { slotG[rr] = tG; slotS[rr] = tS; }
            aG = f4zero(); aS = f4zero();
            cs = bnd;
            ++r;
            if (r >= R_BONDS) { bnd = 0x7fffffff; break; }
            #pragma unroll
            for (int rr = 2; rr <= R_BONDS; ++rr)
                if (r + 1 == rr) bnd = st[rr] - eb;
        }
    };

    int w0 = 0;
    while (w0 < total) {
        int wlen = total - w0; if (wlen > 64) wlen = 64;
        int2 p = make_int2(0, 0);
        if (lane < wlen) p = edges2[eb + w0 + lane];   // one coalesced index window
        const int ng = (wlen + 3) >> 2;

        f4 gA, sA, gB, sB, gC, sC, gD, sD;

#define ISS(QQ, GV, SV) do { \
        if ((QQ) < ng) { \
            const int idx_ = (QQ) * 4 + sg; \
            const int nbr_ = __shfl(p.y, idx_); \
            int qe_ = w0 + idx_; if (qe_ >= total) qe_ = total - 1; \
            GV = bond4[nbr_ * 16 + fl]; \
            SV = sph4[(eb + qe_) * 16 + fl]; \
        } else { GV = f4zero(); SV = f4zero(); } } while (0)

#define ACC(QQ, GV, SV) do { \
        const int q_ = w0 + (QQ) * 4; \
        if (q_ + 4 <= bnd) { aG += GV; aS += SV; } \
        else slowpath(q_, GV, SV); } while (0)

        ISS(0, gA, sA); ISS(1, gB, sB); ISS(2, gC, sC); ISS(3, gD, sD);
        int q = 0;
        for (; q + 4 <= ng; q += 4) {                  // rotated: 8 loads in flight
            ACC(q + 0, gA, sA); ISS(q + 4, gA, sA);
            ACC(q + 1, gB, sB); ISS(q + 5, gB, sB);
            ACC(q + 2, gC, sC); ISS(q + 6, gC, sC);
            ACC(q + 3, gD, sD); ISS(q + 7, gD, sD);
        }
        if (q + 0 < ng) ACC(q + 0, gA, sA);            // tail (<=3 quads)
        if (q + 1 < ng) ACC(q + 1, gB, sB);
        if (q + 2 < ng) ACC(q + 2, gC, sC);
#undef ISS
#undef ACC
        w0 += wlen;
    }

    {   // close remaining open/empty bonds
        const float tG = txr(aG), tS = txr(aS);
        #pragma unroll
        for (int rr = 0; rr < R_BONDS; ++rr) {
            if (rr == r)     { slotG[rr] = tG;  slotS[rr] = tS; }
            else if (rr > r) { slotG[rr] = 0.f; slotS[rr] = 0.f; }
        }
    }

    // ---- deferred matvec: 4 bonds amortize each LDS K read ----
    float acc[R_BONDS];
    const float bl = bias[lane];
    #pragma unroll
    for (int rr = 0; rr < R_BONDS; ++rr) acc[rr] = bl;

    #pragma unroll 4
    for (int d = 0; d < 64; ++d) {
        const float kt = ldsK[d * 64 + lane];          // 2-way bank alias: free
        const float kb = ldsK[(64 + d) * 64 + lane];
        #pragma unroll
        for (int rr = 0; rr < R_BONDS; ++rr) {
            acc[rr] = fmaf(bcastf(slotG[rr], d), kt, acc[rr]);
            acc[rr] = fmaf(bcastf(slotS[rr], d), kb, acc[rr]);
        }
    }

    #pragma unroll
    for (int rr = 0; rr < R_BONDS; ++rr)
        if (b0 + rr < N_BONDS)
            __builtin_nontemporal_store(acc[rr], &out[(b0 + rr) * 64 + lane]);
}

extern "C" void kernel_launch(void* const* d_in, const int* in_sizes, int n_in,
                              void* d_out, int out_size, void* d_ws, size_t ws_size,
                              hipStream_t stream) {
    const float* bond  = (const float*)d_in[0];
    const float* sph   = (const float*)d_in[1];
    const int*   edges = (const int*)d_in[2];
    const float* Kmat  = (const float*)d_in[3];
    const float* bias  = (const float*)d_in[4];
    float* out  = (float*)d_out;
    int* starts = (int*)d_ws;                          // (N_BONDS+1)*4 = 200 KB

    fill_starts<<<(N_EDGES + 255) / 256, 256, 0, stream>>>(edges, starts);

    const int nblocks = (N_BONDS + BONDS_PER_BLOCK - 1) / BONDS_PER_BLOCK;
    fused_gather_segsum_mm<<<nblocks, THREADS, 0, stream>>>(bond, sph, edges, Kmat,
                                                            bias, starts, out);
}